// Round 5
// baseline (145.437 us; speedup 1.0000x reference)
//
#include <hip/hip_runtime.h>
#include <stdint.h>

#define N_ROWS 4096
#define N_DIM  2048
#define MARGIN 0.3f
#define NITER  (N_DIM / 64)  // BK=64 -> 32 K-iterations
#define FLTMAX 3.402823466e+38f

// Tiling: 64 (A-rows) x 128 (B-cols) tiles. bi in [0,64), bj in [0,32),
// keep tiles with bj >= bi/2 (covers all upper-triangle cells) -> 1056 blocks
// (4.125/CU, balanced).
#define NBI 64
#define NBJ 32
#define NBLOCKS 1056         // sum_{bi=0}^{63} (32 - bi/2)

typedef __attribute__((ext_vector_type(8))) short short8;
typedef __attribute__((ext_vector_type(4))) float floatx4;

// Packed layout ("fragment order"): for 16-row group g (256 total) and k-chunk
// c (32 k each, 64 total), a 1 KB block at shorts-offset (g*64+c)*512. Lane l's
// 16 B fragment at l*8 shorts = row g*16+(l&15), k c*32+(l>>4)*8.. (verified
// absmax 0.0). A BK=64 iter uses k-chunks {2it,2it+1}: contiguous 2 KB per
// row-group.

__device__ inline unsigned short f2bf_rne(float f) {
  unsigned u = __float_as_uint(f);
  unsigned r = 0x7fffu + ((u >> 16) & 1u);
  return (unsigned short)((u + r) >> 16);
}
__device__ inline float bf2f(unsigned short h) {
  return __uint_as_float(((unsigned)h) << 16);
}

// Async global->LDS DMA, 16 B per lane. LDS dest = firstlane base + lane*16.
__device__ inline void gld_lds16(const void* g, void* l) {
  __builtin_amdgcn_global_load_lds(
      (const __attribute__((address_space(1))) void*)g,
      (__attribute__((address_space(3))) void*)l, 16, 0, 0);
}

// Counted vmcnt wait (even N, 0..30). Compile-time constant callers only.
__device__ inline void wait_vmcnt_even(int n) {
  switch (n) {
    case 0:  asm volatile("s_waitcnt vmcnt(0)" ::: "memory"); break;
    case 2:  asm volatile("s_waitcnt vmcnt(2)" ::: "memory"); break;
    case 4:  asm volatile("s_waitcnt vmcnt(4)" ::: "memory"); break;
    case 6:  asm volatile("s_waitcnt vmcnt(6)" ::: "memory"); break;
    case 8:  asm volatile("s_waitcnt vmcnt(8)" ::: "memory"); break;
    case 10: asm volatile("s_waitcnt vmcnt(10)" ::: "memory"); break;
    case 12: asm volatile("s_waitcnt vmcnt(12)" ::: "memory"); break;
    case 14: asm volatile("s_waitcnt vmcnt(14)" ::: "memory"); break;
    case 16: asm volatile("s_waitcnt vmcnt(16)" ::: "memory"); break;
    case 18: asm volatile("s_waitcnt vmcnt(18)" ::: "memory"); break;
    case 20: asm volatile("s_waitcnt vmcnt(20)" ::: "memory"); break;
    case 22: asm volatile("s_waitcnt vmcnt(22)" ::: "memory"); break;
    case 24: asm volatile("s_waitcnt vmcnt(24)" ::: "memory"); break;
    case 26: asm volatile("s_waitcnt vmcnt(26)" ::: "memory"); break;
    case 28: asm volatile("s_waitcnt vmcnt(28)" ::: "memory"); break;
    default: asm volatile("s_waitcnt vmcnt(30)" ::: "memory"); break;
  }
}

// ---------------------------------------------------------------------------
// Kernel 1 (UNCHANGED from R4): cast fp32 -> bf16 AND repack into fragment
// order via LDS-DMA streaming; sq from the ROUNDED values (bit-identical
// chain). Counted vmcnt chase of the 32-deep DMA queue.
// ---------------------------------------------------------------------------
__global__ __launch_bounds__(256) void prep_kernel(
    const float* __restrict__ X, unsigned short* __restrict__ Xp,
    float* __restrict__ sq, unsigned* __restrict__ ap, unsigned* __restrict__ an)
{
  __shared__ __align__(16) float chunkf[16][2048];   // 16 x 8 KB = 128 KB
  const int b = blockIdx.x;
  const int t = threadIdx.x;
  const int r = t & 15, j = (t >> 4) & 3, w = t >> 6;

  const char* Xb = (const char*)(X + (size_t)b * 16 * N_DIM);
#pragma unroll
  for (int s = 0; s < 16; ++s) {
#pragma unroll
    for (int q = 0; q < 2; ++q) {
      const unsigned v = q * 256 + t;
      const unsigned rr = v >> 5, slot = v & 31, u = slot ^ (rr & 7);
      gld_lds16(Xb + (size_t)rr * 8192 + s * 512 + u * 16, &chunkf[s][v * 4]);
    }
  }
  __builtin_amdgcn_sched_barrier(0);   // pin all 32 DMA issues above the waits

  unsigned short* Op = Xp + (size_t)b * 64 * 512 + (size_t)(j * 16 + r) * 8;
  const unsigned u0 = (unsigned)(w * 8 + j * 2);
  const unsigned sl0 = (r * 32 + (u0 ^ (r & 7))) * 4;        // float index
  const unsigned sl1 = (r * 32 + ((u0 + 1) ^ (r & 7))) * 4;

  float acc = 0.f;
#pragma unroll
  for (int s = 0; s < 16; ++s) {
    wait_vmcnt_even(30 - 2 * s);       // chunk s's 2 ops retired (in-order)
    __builtin_amdgcn_sched_barrier(0);
    const int c = w + s * 4;
    float4 v0 = *(const float4*)&chunkf[s][sl0];
    float4 v1 = *(const float4*)&chunkf[s][sl1];
    short8 o;
    o[0] = (short)f2bf_rne(v0.x); o[1] = (short)f2bf_rne(v0.y);
    o[2] = (short)f2bf_rne(v0.z); o[3] = (short)f2bf_rne(v0.w);
    o[4] = (short)f2bf_rne(v1.x); o[5] = (short)f2bf_rne(v1.y);
    o[6] = (short)f2bf_rne(v1.z); o[7] = (short)f2bf_rne(v1.w);
#pragma unroll
    for (int e = 0; e < 8; ++e) {
      float f = bf2f((unsigned short)o[e]);
      acc = fmaf(f, f, acc);
    }
    *(short8*)(Op + (size_t)c * 512) = o;
  }
  acc += __shfl_xor(acc, 16, 64);
  acc += __shfl_xor(acc, 32, 64);
  __shared__ float part[4][16];
  if ((t & 63) < 16) part[w][r] = acc;
  __syncthreads();
  if (t < 16) {
    float s4 = part[0][t] + part[1][t] + part[2][t] + part[3][t];
    sq[b * 16 + t] = s4;
    ap[b * 16 + t] = 0u;           // max identity (dist >= 0)
    an[b * 16 + t] = 0x7f7fffffu;  // FLT_MAX bits
  }
}

// ---------------------------------------------------------------------------
// Kernel 2, R5: same geometry as R3/R4 (64x128 tile, 1x4 wave grid, acc[4][2],
// A in LDS via gld_lds, B direct-to-register) but the per-iter FULL DRAIN
// (__syncthreads = vmcnt(0)+lgkmcnt(0)) is replaced by a counted-vmcnt
// pipeline (T3/T4):
//   - As is a 4-deep ring; DMA for iter it+2 is issued at iter it (2 phases
//     of flight time).
//   - per-iter: s_waitcnt vmcnt(6) [retires exactly dma(it)] + raw s_barrier;
//     issue bn(it+1) then dma(it+2) (order pinned by sched_barrier(0));
//     s_waitcnt vmcnt(8) [retires exactly bn(it)]; ds_read+MFMA.
//     dma(it+1), bn(it+1), dma(it+2) stay in flight across the barrier.
//   - WAR safety: dma targeting As[x] is issued 2 barriers after the last
//     ds_read of As[x]; ds_read data is consumed (lgkm-waited by MFMA use)
//     before the issuing wave reaches the next barrier.
//   - B regs ping-pong bnA/bnB via 2-iter unroll (static indices).
// Arithmetic (MFMA order, epilogue) is bit-identical to R3/R4.
// ---------------------------------------------------------------------------
__global__ __launch_bounds__(256, 4) void dist_kernel(
    const unsigned short* __restrict__ Xp, const float* __restrict__ sq,
    const int* __restrict__ lab, unsigned* __restrict__ ap, unsigned* __restrict__ an)
{
  __shared__ __align__(16) unsigned short As[4][4096];   // 4 x 8 KB ring
  __shared__ float sqi[64], sqj[128];
  __shared__ int labi[64], labj[128];

  // decode linear block id -> (bi, bj) with bj >= bi/2
  int p = blockIdx.x;
  int bi = 0;
  while (p >= NBJ - (bi >> 1)) { p -= NBJ - (bi >> 1); ++bi; }
  const int bj = (bi >> 1) + p;

  const int t = threadIdx.x;
  const int lane = t & 63, w = t >> 6;     // 4 waves, 1x4 grid: wave w owns
                                           // cols [w*32, w*32+32), all 64 rows

  if (t < 64)       { int rr = bi * 64 + t;         sqi[t] = sq[rr];        labi[t] = lab[rr]; }
  else if (t < 192) { int cc = bj * 128 + (t - 64); sqj[t - 64] = sq[cc];   labj[t - 64] = lab[cc]; }
  __builtin_amdgcn_sched_barrier(0);   // sq/lab loads consumed above; vmcnt ledger clean

  // A staging: identity chunk map, 512 x 16B units (2/thread). unit u: group
  // gg = u>>7 (wave-uniform), off = u&127 (lane-contiguous) -> legal gld_lds.
  unsigned gA[2], loA[2];
#pragma unroll
  for (int q = 0; q < 2; ++q) {
    const unsigned u = q * 256 + t;
    gA[q] = ((unsigned)(bi * 4 + (u >> 7)) * 64) * 512 + (u & 127) * 8;
    loA[q] = u * 8;
  }
  // B direct: wave w's col 16-groups are (w*2) and (w*2+1). Fragment for
  // (ni, it, kh) at Bb[ni] + it*1024 + kh*512 (shorts), per-lane 16 B.
  const unsigned short* Bb[2];
#pragma unroll
  for (int ni = 0; ni < 2; ++ni)
    Bb[ni] = Xp + ((size_t)(unsigned)(bj * 8 + w * 2 + ni) * 64) * 512 + (unsigned)lane * 8;

#define SB() __builtin_amdgcn_sched_barrier(0)
#define BAR() __builtin_amdgcn_s_barrier()
#define STAGE(IT)                                                            \
  do {                                                                       \
    unsigned short* dst_ = &As[(IT) & 3][0];                                 \
    _Pragma("unroll")                                                        \
    for (int q = 0; q < 2; ++q)                                              \
      gld_lds16(Xp + gA[q] + (unsigned)(IT) * 1024u, dst_ + loA[q]);         \
  } while (0)
#define BLOAD(DST, IT)                                                       \
  do {                                                                       \
    _Pragma("unroll")                                                        \
    for (int ni = 0; ni < 2; ++ni)                                           \
      _Pragma("unroll")                                                      \
      for (int kh = 0; kh < 2; ++kh)                                         \
        DST[ni][kh] = *(const short8*)(Bb[ni] + (unsigned)(IT) * 1024u +     \
                                       kh * 512);                            \
  } while (0)
#define COMPUTE(IT, BN)                                                      \
  do {                                                                       \
    const unsigned short* Asrc_ = &As[(IT) & 3][0];                          \
    _Pragma("unroll")                                                        \
    for (int kh = 0; kh < 2; ++kh) {                                         \
      short8 af[4];                                                          \
      _Pragma("unroll")                                                      \
      for (int mi = 0; mi < 4; ++mi)                                         \
        af[mi] = *(const short8*)&Asrc_[(mi * 2 + kh) * 512 + lane * 8];     \
      _Pragma("unroll")                                                      \
      for (int mi = 0; mi < 4; ++mi)                                         \
        _Pragma("unroll")                                                    \
        for (int ni = 0; ni < 2; ++ni)                                       \
          acc[mi][ni] = __builtin_amdgcn_mfma_f32_16x16x32_bf16(             \
              af[mi], BN[ni][kh], acc[mi][ni], 0, 0, 0);                     \
    }                                                                        \
  } while (0)

  floatx4 acc[4][2] = {};
  short8 bnA[2][2], bnB[2][2];

  // Prologue issue order (the ledger's oldest->newest): dma(0), bn(0), dma(1).
  STAGE(0); SB();
  BLOAD(bnA, 0); SB();
  STAGE(1); SB();
  asm volatile("s_waitcnt lgkmcnt(0)" ::: "memory");  // sqi/sqj ds_writes done
  SB();

  // Steady loop: it = 0..29, 2 iters per body (bnA even / bnB odd).
  for (int it2 = 0; it2 < 15; ++it2) {
    const int itE = it2 * 2;
    // even iter itE: outstanding {dma(itE):2, bn(itE):4, dma(itE+1):2}
    wait_vmcnt_even(6); BAR(); SB();
    BLOAD(bnB, itE + 1); SB();
    STAGE(itE + 2); SB();
    wait_vmcnt_even(8); SB();          // bn(itE) retired
    COMPUTE(itE, bnA);
    // odd iter itE+1: outstanding {dma(itE+1):2, bn(itE+1):4, dma(itE+2):2}
    wait_vmcnt_even(6); BAR(); SB();
    BLOAD(bnA, itE + 3); SB();
    STAGE(itE + 3); SB();
    wait_vmcnt_even(8); SB();          // bn(itE+1) retired
    COMPUTE(itE + 1, bnB);
  }

  // it = 30 (even): no dma(32). outstanding {dma(30):2, bn(30):4, dma(31):2}
  wait_vmcnt_even(6); BAR(); SB();
  BLOAD(bnB, 31); SB();
  wait_vmcnt_even(6); SB();            // bn(30) retired; dma(31)+bn(31) fly
  COMPUTE(30, bnA);
  // it = 31 (odd): outstanding {dma(31):2, bn(31):4}
  wait_vmcnt_even(4); BAR(); SB();
  wait_vmcnt_even(0); SB();            // bn(31) retired
  COMPUTE(31, bnB);

#undef SB
#undef BAR
#undef STAGE
#undef BLOAD
#undef COMPUTE

  // Epilogue. C/D layout (m89): col = lane&15, row = (lane>>4)*4 + reg.
  const int cn = lane & 15, lg = lane >> 4;
  float sqc[2]; int labc[2];
#pragma unroll
  for (int ni = 0; ni < 2; ++ni) {
    int c = w * 32 + ni * 16 + cn;
    sqc[ni] = sqj[c]; labc[ni] = labj[c];
  }
  float cap[2] = {0.f, 0.f};
  float can[2] = {FLTMAX, FLTMAX};
#pragma unroll
  for (int mi = 0; mi < 4; ++mi) {
#pragma unroll
    for (int r = 0; r < 4; ++r) {
      const int rl = mi * 16 + lg * 4 + r;   // row within 64-tile
      const float si = sqi[rl];
      const int li = labi[rl];
      float apv = 0.0f;
      float anv = FLTMAX;
#pragma unroll
      for (int ni = 0; ni < 2; ++ni) {
        float g = acc[mi][ni][r];
        float d2 = fmaf(-2.0f, g, si + sqc[ni]);
        d2 = fmaxf(d2, 1e-12f);
        float d = __builtin_amdgcn_sqrtf(d2);
        const bool same = (li == labc[ni]);
        const float dp = same ? d : 0.0f;
        const float dn = same ? FLTMAX : d;
        apv = fmaxf(apv, dp);
        anv = fminf(anv, dn);
        cap[ni] = fmaxf(cap[ni], dp);   // col-side (symmetric) partials
        can[ni] = fminf(can[ni], dn);
      }
      // row side: reduce over the 16 cn-lanes (same lg = same row)
#pragma unroll
      for (int m = 8; m >= 1; m >>= 1) {
        apv = fmaxf(apv, __shfl_xor(apv, m, 64));
        anv = fminf(anv, __shfl_xor(anv, m, 64));
      }
      if (cn == 0) {
        int R = bi * 64 + rl;
        atomicMax(&ap[R], __float_as_uint(apv));
        atomicMin(&an[R], __float_as_uint(anv));
      }
    }
  }
  // col side: reduce over lg (xor 16,32) -> full 64 rows per column
#pragma unroll
  for (int ni = 0; ni < 2; ++ni) {
    float a = cap[ni], b = can[ni];
#pragma unroll
    for (int m = 16; m <= 32; m <<= 1) {
      a = fmaxf(a, __shfl_xor(a, m, 64));
      b = fminf(b, __shfl_xor(b, m, 64));
    }
    if (lg == 0) {
      int C = bj * 128 + w * 32 + ni * 16 + cn;
      atomicMax(&ap[C], __float_as_uint(a));
      atomicMin(&an[C], __float_as_uint(b));
    }
  }
}

// ---------------------------------------------------------------------------
// Kernel 3 (UNCHANGED from R4): loss = mean(relu(margin + dist_ap - dist_an))
// ---------------------------------------------------------------------------
__global__ __launch_bounds__(256) void finalize_kernel(
    const unsigned* __restrict__ ap, const unsigned* __restrict__ an,
    float* __restrict__ out)
{
  const int t = threadIdx.x;
  float av[16], bv[16];
#pragma unroll
  for (int q = 0; q < 16; ++q) {
    av[q] = __uint_as_float(ap[t + q * 256]);
    bv[q] = __uint_as_float(an[t + q * 256]);
  }
  float s = 0.f;
#pragma unroll
  for (int q = 0; q < 16; ++q) s += fmaxf(MARGIN + av[q] - bv[q], 0.0f);
#pragma unroll
  for (int m = 32; m >= 1; m >>= 1) s += __shfl_down(s, m, 64);
  __shared__ float wsum[4];
  const int lane = t & 63, w = t >> 6;
  if (lane == 0) wsum[w] = s;
  __syncthreads();
  if (t == 0) out[0] = (wsum[0] + wsum[1] + wsum[2] + wsum[3]) * (1.0f / N_ROWS);
}

extern "C" void kernel_launch(void* const* d_in, const int* in_sizes, int n_in,
                              void* d_out, int out_size, void* d_ws, size_t ws_size,
                              hipStream_t stream) {
  const float* X = (const float*)d_in[0];
  const int* lab = (const int*)d_in[1];
  float* out = (float*)d_out;

  char* ws = (char*)d_ws;
  unsigned short* Xp = (unsigned short*)ws;                           // 16 MB packed
  float* sq  = (float*)(ws + (size_t)N_ROWS * N_DIM * 2);             // 16 KB
  unsigned* ap = (unsigned*)((char*)sq + N_ROWS * sizeof(float));     // 16 KB
  unsigned* an = (unsigned*)((char*)ap + N_ROWS * sizeof(unsigned));  // 16 KB

  prep_kernel<<<N_ROWS / 16, 256, 0, stream>>>(X, Xp, sq, ap, an);
  dist_kernel<<<NBLOCKS, 256, 0, stream>>>(Xp, sq, lab, ap, an);
  finalize_kernel<<<1, 256, 0, stream>>>(ap, an, out);
}

// Round 7
// 142.065 us; speedup vs baseline: 1.0237x; 1.0237x over previous
//
#include <hip/hip_runtime.h>
#include <stdint.h>

#define N_ROWS 4096
#define N_DIM  2048
#define MARGIN 0.3f
#define NPHASE 16            // BK=128 -> 16 barrier phases (2 K-steps each)
#define FLTMAX 3.402823466e+38f

// Tiling: 64 (A-rows) x 128 (B-cols) tiles. bi in [0,64), bj in [0,32),
// keep tiles with bj >= bi/2 (covers all upper-triangle cells) -> 1056 blocks
// (4.125/CU, balanced).
#define NBI 64
#define NBJ 32
#define NBLOCKS 1056         // sum_{bi=0}^{63} (32 - bi/2)

typedef __attribute__((ext_vector_type(8))) short short8;
typedef __attribute__((ext_vector_type(4))) float floatx4;

// Packed layout ("fragment order"): for 16-row group g (256 total) and k-chunk
// c (32 k each, 64 total), a 1 KB block at shorts-offset (g*64+c)*512. Lane l's
// 16 B fragment at l*8 shorts = row g*16+(l&15), k c*32+(l>>4)*8.. (verified
// absmax 0.0 through R4). Chunks are contiguous per group: chunk range
// [4*it2, 4*it2+4) is one contiguous 2 KB span per row-group.

__device__ inline unsigned short f2bf_rne(float f) {
  unsigned u = __float_as_uint(f);
  unsigned r = 0x7fffu + ((u >> 16) & 1u);
  return (unsigned short)((u + r) >> 16);
}
__device__ inline float bf2f(unsigned short h) {
  return __uint_as_float(((unsigned)h) << 16);
}

// Async global->LDS DMA, 16 B per lane. LDS dest = firstlane base + lane*16.
__device__ inline void gld_lds16(const void* g, void* l) {
  __builtin_amdgcn_global_load_lds(
      (const __attribute__((address_space(1))) void*)g,
      (__attribute__((address_space(3))) void*)l, 16, 0, 0);
}

// Counted vmcnt wait (even N, 0..30). Compile-time constant callers only.
// (Used ONLY in prep_kernel's single-wave DMA chase — the R5 attempt to use
// counted waits in dist_kernel regressed (sched-pinning, m141-style) and is
// reverted.)
__device__ inline void wait_vmcnt_even(int n) {
  switch (n) {
    case 0:  asm volatile("s_waitcnt vmcnt(0)" ::: "memory"); break;
    case 2:  asm volatile("s_waitcnt vmcnt(2)" ::: "memory"); break;
    case 4:  asm volatile("s_waitcnt vmcnt(4)" ::: "memory"); break;
    case 6:  asm volatile("s_waitcnt vmcnt(6)" ::: "memory"); break;
    case 8:  asm volatile("s_waitcnt vmcnt(8)" ::: "memory"); break;
    case 10: asm volatile("s_waitcnt vmcnt(10)" ::: "memory"); break;
    case 12: asm volatile("s_waitcnt vmcnt(12)" ::: "memory"); break;
    case 14: asm volatile("s_waitcnt vmcnt(14)" ::: "memory"); break;
    case 16: asm volatile("s_waitcnt vmcnt(16)" ::: "memory"); break;
    case 18: asm volatile("s_waitcnt vmcnt(18)" ::: "memory"); break;
    case 20: asm volatile("s_waitcnt vmcnt(20)" ::: "memory"); break;
    case 22: asm volatile("s_waitcnt vmcnt(22)" ::: "memory"); break;
    case 24: asm volatile("s_waitcnt vmcnt(24)" ::: "memory"); break;
    case 26: asm volatile("s_waitcnt vmcnt(26)" ::: "memory"); break;
    case 28: asm volatile("s_waitcnt vmcnt(28)" ::: "memory"); break;
    default: asm volatile("s_waitcnt vmcnt(30)" ::: "memory"); break;
  }
}

// ---------------------------------------------------------------------------
// Kernel 1 (UNCHANGED from R4): cast fp32 -> bf16 AND repack into fragment
// order via LDS-DMA streaming; sq from the ROUNDED values (bit-identical
// chain). Counted vmcnt chase of the 32-deep DMA queue.
// ---------------------------------------------------------------------------
__global__ __launch_bounds__(256) void prep_kernel(
    const float* __restrict__ X, unsigned short* __restrict__ Xp,
    float* __restrict__ sq, unsigned* __restrict__ ap, unsigned* __restrict__ an)
{
  __shared__ __align__(16) float chunkf[16][2048];   // 16 x 8 KB = 128 KB
  const int b = blockIdx.x;
  const int t = threadIdx.x;
  const int r = t & 15, j = (t >> 4) & 3, w = t >> 6;

  const char* Xb = (const char*)(X + (size_t)b * 16 * N_DIM);
#pragma unroll
  for (int s = 0; s < 16; ++s) {
#pragma unroll
    for (int q = 0; q < 2; ++q) {
      const unsigned v = q * 256 + t;
      const unsigned rr = v >> 5, slot = v & 31, u = slot ^ (rr & 7);
      gld_lds16(Xb + (size_t)rr * 8192 + s * 512 + u * 16, &chunkf[s][v * 4]);
    }
  }
  __builtin_amdgcn_sched_barrier(0);   // pin all 32 DMA issues above the waits

  unsigned short* Op = Xp + (size_t)b * 64 * 512 + (size_t)(j * 16 + r) * 8;
  const unsigned u0 = (unsigned)(w * 8 + j * 2);
  const unsigned sl0 = (r * 32 + (u0 ^ (r & 7))) * 4;        // float index
  const unsigned sl1 = (r * 32 + ((u0 + 1) ^ (r & 7))) * 4;

  float acc = 0.f;
#pragma unroll
  for (int s = 0; s < 16; ++s) {
    wait_vmcnt_even(30 - 2 * s);       // chunk s's 2 ops retired (in-order)
    __builtin_amdgcn_sched_barrier(0);
    const int c = w + s * 4;
    float4 v0 = *(const float4*)&chunkf[s][sl0];
    float4 v1 = *(const float4*)&chunkf[s][sl1];
    short8 o;
    o[0] = (short)f2bf_rne(v0.x); o[1] = (short)f2bf_rne(v0.y);
    o[2] = (short)f2bf_rne(v0.z); o[3] = (short)f2bf_rne(v0.w);
    o[4] = (short)f2bf_rne(v1.x); o[5] = (short)f2bf_rne(v1.y);
    o[6] = (short)f2bf_rne(v1.z); o[7] = (short)f2bf_rne(v1.w);
#pragma unroll
    for (int e = 0; e < 8; ++e) {
      float f = bf2f((unsigned short)o[e]);
      acc = fmaf(f, f, acc);
    }
    *(short8*)(Op + (size_t)c * 512) = o;
  }
  acc += __shfl_xor(acc, 16, 64);
  acc += __shfl_xor(acc, 32, 64);
  __shared__ float part[4][16];
  if ((t & 63) < 16) part[w][r] = acc;
  __syncthreads();
  if (t < 16) {
    float s4 = part[0][t] + part[1][t] + part[2][t] + part[3][t];
    sq[b * 16 + t] = s4;
    ap[b * 16 + t] = 0u;           // max identity (dist >= 0)
    an[b * 16 + t] = 0x7f7fffffu;  // FLT_MAX bits
  }
}

// ---------------------------------------------------------------------------
// Kernel 2, R6: R3's proven structure (64x128 tile, 1x4 wave grid, acc[4][2],
// A in LDS via gld_lds, B direct-to-register, __syncthreads semantics) with
// BK=128 per barrier phase: two K-steps (chunks 4p..4p+3) per SINGLE
// __syncthreads -> 16 barrier drains instead of 32. LDS: As[2][16 KB] dbuf
// (34 KB total, still 4 blocks/CU; grid-limited anyway). B regs: bc (subiter
// h=0) is reloaded for the NEXT phase right after its last consuming MFMA
// (in-order issue makes the register WAR safe), bn1 holds h=1 -> live B-reg
// count unchanged vs R3. Chunk order 4p,4p+1,4p+2,4p+3 with the same
// (kh,mi,ni) MFMA order = exactly two R3 iterations -> bit-identical acc.
// ---------------------------------------------------------------------------
__global__ __launch_bounds__(256, 4) void dist_kernel(
    const unsigned short* __restrict__ Xp, const float* __restrict__ sq,
    const int* __restrict__ lab, unsigned* __restrict__ ap, unsigned* __restrict__ an)
{
  __shared__ __align__(16) unsigned short As[2][8192];   // 2 x 16 KB (BK=128)
  __shared__ float sqi[64], sqj[128];
  __shared__ int labi[64], labj[128];

  // decode linear block id -> (bi, bj) with bj >= bi/2
  int p = blockIdx.x;
  int bi = 0;
  while (p >= NBJ - (bi >> 1)) { p -= NBJ - (bi >> 1); ++bi; }
  const int bj = (bi >> 1) + p;

  const int t = threadIdx.x;
  const int lane = t & 63, w = t >> 6;     // 4 waves, 1x4 grid: wave w owns
                                           // cols [w*32, w*32+32), all 64 rows

  if (t < 64)       { int rr = bi * 64 + t;         sqi[t] = sq[rr];        labi[t] = lab[rr]; }
  else if (t < 192) { int cc = bj * 128 + (t - 64); sqj[t - 64] = sq[cc];   labj[t - 64] = lab[cc]; }

  // A staging, 1024 x 16B units (4/thread) per phase. Unit u: seg = u>>6
  // (wave-uniform: seg = q*4 + w), off = u&63 (= lane, contiguous).
  // seg decomposes as h = seg>>3 (sub-K-step), mi = (seg>>1)&3 (row-group),
  // kh = seg&1; global chunk = 4*phase + 2*h + kh. LDS dest linear in u ->
  // legal gld_lds; each wave's op is one contiguous 1 KB global read.
  // ds_read address for (h, mi, kh): ((h*8 + mi*2 + kh)*512 + lane*8) --
  // h=0 half is bit-for-bit R3's layout, h=1 half at +4096.
  unsigned gA[4], loA[4];
#pragma unroll
  for (int q = 0; q < 4; ++q) {
    const unsigned u = q * 256 + t;
    const unsigned seg = u >> 6, off = u & 63;
    const unsigned h = seg >> 3, mi = (seg >> 1) & 3, kh = seg & 1;
    gA[q] = ((unsigned)(bi * 4 + mi) * 64 + 2 * h + kh) * 512 + off * 8;
    loA[q] = u * 8;
  }
  // B direct: wave w's col 16-groups are (w*2) and (w*2+1). Fragment for
  // chunk c at Bb[ni] + c*512 (shorts), per-lane 16 B.
  const unsigned short* Bb[2];
#pragma unroll
  for (int ni = 0; ni < 2; ++ni)
    Bb[ni] = Xp + ((size_t)(unsigned)(bj * 8 + w * 2 + ni) * 64) * 512 + (unsigned)lane * 8;

#define STAGE_A(BUF, PH)                                                     \
  do {                                                                       \
    _Pragma("unroll")                                                        \
    for (int q = 0; q < 4; ++q)                                              \
      gld_lds16(Xp + gA[q] + (unsigned)(PH) * 2048u, &As[BUF][loA[q]]);      \
  } while (0)
#define BLOAD(DST, CBASE)                                                    \
  do {                                                                       \
    _Pragma("unroll")                                                        \
    for (int ni = 0; ni < 2; ++ni)                                           \
      _Pragma("unroll")                                                      \
      for (int kh = 0; kh < 2; ++kh)                                         \
        DST[ni][kh] = *(const short8*)(Bb[ni] +                              \
                                       (unsigned)((CBASE) + kh) * 512u);     \
  } while (0)
#define COMPUTE(CUR, H, BN)                                                  \
  do {                                                                       \
    const unsigned short* Asrc_ = &As[CUR][(H) * 4096];                      \
    _Pragma("unroll")                                                        \
    for (int kh = 0; kh < 2; ++kh) {                                         \
      short8 af[4];                                                          \
      _Pragma("unroll")                                                      \
      for (int mi = 0; mi < 4; ++mi)                                         \
        af[mi] = *(const short8*)&Asrc_[(mi * 2 + kh) * 512 + lane * 8];     \
      _Pragma("unroll")                                                      \
      for (int mi = 0; mi < 4; ++mi)                                         \
        _Pragma("unroll")                                                    \
        for (int ni = 0; ni < 2; ++ni)                                       \
          acc[mi][ni] = __builtin_amdgcn_mfma_f32_16x16x32_bf16(             \
              af[mi], BN[ni][kh], acc[mi][ni], 0, 0, 0);                     \
    }                                                                        \
  } while (0)

  floatx4 acc[4][2] = {};
  short8 bc[2][2], bn1[2][2];

  STAGE_A(0, 0);
  BLOAD(bc, 0);                          // chunks 0,1 (phase 0, h=0)
  __syncthreads();                       // DMA drained + sqi/sqj visible

  for (int ph = 0; ph < NPHASE; ++ph) {
    const int cur = ph & 1;
    const bool has_next = (ph + 1 < NPHASE);
    if (has_next) STAGE_A(cur ^ 1, ph + 1);    // async DMA into other buffer
    BLOAD(bn1, 4 * ph + 2);                    // this phase's h=1 fragments
    COMPUTE(cur, 0, bc);                       // chunks 4ph, 4ph+1
    if (has_next) BLOAD(bc, 4 * ph + 4);       // next phase's h=0 (reg WAR
                                               // safe: bc's MFMAs issued)
    COMPUTE(cur, 1, bn1);                      // chunks 4ph+2, 4ph+3
    // ONE barrier per 2 K-steps: drains the DMA into As[cur^1] and the B
    // loads; all waves' As[cur] reads done before it's overwritten next.
    __syncthreads();
  }
#undef STAGE_A
#undef BLOAD
#undef COMPUTE

  // Epilogue. C/D layout (m89): col = lane&15, row = (lane>>4)*4 + reg.
  const int cn = lane & 15, lg = lane >> 4;
  float sqc[2]; int labc[2];
#pragma unroll
  for (int ni = 0; ni < 2; ++ni) {
    int c = w * 32 + ni * 16 + cn;
    sqc[ni] = sqj[c]; labc[ni] = labj[c];
  }
  float cap[2] = {0.f, 0.f};
  float can[2] = {FLTMAX, FLTMAX};
#pragma unroll
  for (int mi = 0; mi < 4; ++mi) {
#pragma unroll
    for (int r = 0; r < 4; ++r) {
      const int rl = mi * 16 + lg * 4 + r;   // row within 64-tile
      const float si = sqi[rl];
      const int li = labi[rl];
      float apv = 0.0f;
      float anv = FLTMAX;
#pragma unroll
      for (int ni = 0; ni < 2; ++ni) {
        float g = acc[mi][ni][r];
        float d2 = fmaf(-2.0f, g, si + sqc[ni]);
        d2 = fmaxf(d2, 1e-12f);
        float d = __builtin_amdgcn_sqrtf(d2);
        const bool same = (li == labc[ni]);
        const float dp = same ? d : 0.0f;
        const float dn = same ? FLTMAX : d;
        apv = fmaxf(apv, dp);
        anv = fminf(anv, dn);
        cap[ni] = fmaxf(cap[ni], dp);   // col-side (symmetric) partials
        can[ni] = fminf(can[ni], dn);
      }
      // row side: reduce over the 16 cn-lanes (same lg = same row)
#pragma unroll
      for (int m = 8; m >= 1; m >>= 1) {
        apv = fmaxf(apv, __shfl_xor(apv, m, 64));
        anv = fminf(anv, __shfl_xor(anv, m, 64));
      }
      if (cn == 0) {
        int R = bi * 64 + rl;
        atomicMax(&ap[R], __float_as_uint(apv));
        atomicMin(&an[R], __float_as_uint(anv));
      }
    }
  }
  // col side: reduce over lg (xor 16,32) -> full 64 rows per column
#pragma unroll
  for (int ni = 0; ni < 2; ++ni) {
    float a = cap[ni], b = can[ni];
#pragma unroll
    for (int m = 16; m <= 32; m <<= 1) {
      a = fmaxf(a, __shfl_xor(a, m, 64));
      b = fminf(b, __shfl_xor(b, m, 64));
    }
    if (lg == 0) {
      int C = bj * 128 + w * 32 + ni * 16 + cn;
      atomicMax(&ap[C], __float_as_uint(a));
      atomicMin(&an[C], __float_as_uint(b));
    }
  }
}

// ---------------------------------------------------------------------------
// Kernel 3 (UNCHANGED from R4): loss = mean(relu(margin + dist_ap - dist_an))
// ---------------------------------------------------------------------------
__global__ __launch_bounds__(256) void finalize_kernel(
    const unsigned* __restrict__ ap, const unsigned* __restrict__ an,
    float* __restrict__ out)
{
  const int t = threadIdx.x;
  float av[16], bv[16];
#pragma unroll
  for (int q = 0; q < 16; ++q) {
    av[q] = __uint_as_float(ap[t + q * 256]);
    bv[q] = __uint_as_float(an[t + q * 256]);
  }
  float s = 0.f;
#pragma unroll
  for (int q = 0; q < 16; ++q) s += fmaxf(MARGIN + av[q] - bv[q], 0.0f);
#pragma unroll
  for (int m = 32; m >= 1; m >>= 1) s += __shfl_down(s, m, 64);
  __shared__ float wsum[4];
  const int lane = t & 63, w = t >> 6;
  if (lane == 0) wsum[w] = s;
  __syncthreads();
  if (t == 0) out[0] = (wsum[0] + wsum[1] + wsum[2] + wsum[3]) * (1.0f / N_ROWS);
}

extern "C" void kernel_launch(void* const* d_in, const int* in_sizes, int n_in,
                              void* d_out, int out_size, void* d_ws, size_t ws_size,
                              hipStream_t stream) {
  const float* X = (const float*)d_in[0];
  const int* lab = (const int*)d_in[1];
  float* out = (float*)d_out;

  char* ws = (char*)d_ws;
  unsigned short* Xp = (unsigned short*)ws;                           // 16 MB packed
  float* sq  = (float*)(ws + (size_t)N_ROWS * N_DIM * 2);             // 16 KB
  unsigned* ap = (unsigned*)((char*)sq + N_ROWS * sizeof(float));     // 16 KB
  unsigned* an = (unsigned*)((char*)ap + N_ROWS * sizeof(unsigned));  // 16 KB

  prep_kernel<<<N_ROWS / 16, 256, 0, stream>>>(X, Xp, sq, ap, an);
  dist_kernel<<<NBLOCKS, 256, 0, stream>>>(Xp, sq, lab, ap, an);
  finalize_kernel<<<1, 256, 0, stream>>>(ap, an, out);
}